// Round 5
// baseline (73.164 us; speedup 1.0000x reference)
//
#include <hip/hip_runtime.h>
#include <hip/hip_bf16.h>
#include <math.h>

// CoSent clustering loss on MI355X — round 5.
// Same structure as round 4 (triangular 128x128 tiles, register-A + LDS-B,
// one barrier, barrier-free K-loop) PLUS:
//  * asm keep-alive on the 32 hoisted A fragments — forces them to stay in
//    VGPRs so the K-loop has NO global loads (round 4: compiler sank them,
//    VGPR_Count=108 proved it).
//  * s_setprio(1) around MFMA clusters (independent waves, attn-like T5).

typedef __bf16 bf16;
typedef __attribute__((ext_vector_type(4))) __bf16 bf16x4;
typedef __attribute__((ext_vector_type(8))) __bf16 bf16x8;
typedef __attribute__((ext_vector_type(4))) float f32x4;

#define N_EMB 8192
#define D_EMB 256
#define NUM_LABELS 128
#define PAN 128
#define NPAN (N_EMB / PAN)           // 64
#define NTRI (NPAN * (NPAN + 1) / 2) // 2080

// ---- DPP 16-lane reduction helpers ----
template <int CTRL>
__device__ __forceinline__ float dpp_add(float x) {
    int y = __builtin_amdgcn_update_dpp(0, __builtin_bit_cast(int, x),
                                        CTRL, 0xF, 0xF, false);
    return x + __builtin_bit_cast(float, y);
}
__device__ __forceinline__ float red16(float x) {
    x = dpp_add<0xB1>(x);    // quad_perm xor1
    x = dpp_add<0x4E>(x);    // quad_perm xor2
    x = dpp_add<0x124>(x);   // row_ror:4
    x = dpp_add<0x128>(x);   // row_ror:8
    return x;
}

__device__ __forceinline__ unsigned packbf(float a, float b) {
    unsigned ua = __builtin_bit_cast(unsigned, a);
    unsigned ub = __builtin_bit_cast(unsigned, b);
    ua += 0x7FFFu + ((ua >> 16) & 1u);   // RTNE to bf16
    ub += 0x7FFFu + ((ub >> 16) & 1u);
    return (ua >> 16) | (ub & 0xFFFF0000u);
}

// ---------------------------------------------------------------- normalize
__global__ __launch_bounds__(256) void normalize_kernel(const float* __restrict__ emb,
                                                        bf16* __restrict__ e16) {
    const int wid = threadIdx.x >> 6, lane = threadIdx.x & 63;
    const int row = blockIdx.x * 4 + wid;
    const f32x4 x = *(const f32x4*)(emb + (size_t)row * D_EMB + lane * 4);
    float ss = x[0]*x[0] + x[1]*x[1] + x[2]*x[2] + x[3]*x[3];
    #pragma unroll
    for (int off = 32; off >= 1; off >>= 1) ss += __shfl_xor(ss, off);
    const float r = 1.0f / fmaxf(sqrtf(ss), 1e-12f);
    bf16x4 o;
    #pragma unroll
    for (int i = 0; i < 4; ++i) o[i] = (bf16)(x[i] * r);
    *(bf16x4*)(e16 + (size_t)row * D_EMB + lane * 4) = o;
}

// ------------------------------------------------------- async global->LDS
__device__ __forceinline__ void gload_lds16(const bf16* gsrc, bf16* ldst) {
    __builtin_amdgcn_global_load_lds(
        (const __attribute__((address_space(1))) void*)gsrc,
        (__attribute__((address_space(3))) void*)ldst, 16, 0, 0);
}

// ----------------------------------------------------------------- main GEMM
__global__ __launch_bounds__(256, 2) void cosent_main(const bf16* __restrict__ e,
                                                      const int* __restrict__ labels,
                                                      const float* __restrict__ scale,
                                                      unsigned* __restrict__ wsAB) {
    __shared__ bf16 bufB[PAN * D_EMB];      // 64 KB
    __shared__ float rowsc[2][PAN][2];
    __shared__ float colsc[2][PAN][2];
    __shared__ int labR[PAN], labC[PAN];

    // triangular decode: by <= bx
    int rem = blockIdx.x, by = 0;
    while (rem >= NPAN - by) { rem -= NPAN - by; ++by; }
    const int bx = by + rem;
    const bool diag = (bx == by);
    const int rowBase = by * PAN, colBase = bx * PAN;

    const int tid = threadIdx.x, lane = tid & 63, wid = tid >> 6;
    const int wm = wid >> 1, wn = wid & 1;
    const int rr = lane & 15, kh = lane >> 4;

    if (tid < PAN) labR[tid] = labels[rowBase + tid];
    else           labC[tid - PAN] = labels[colBase + tid - PAN];

    // ---- stage B panel (once, full K) with pre-swizzled source ----
    #pragma unroll
    for (int i = 0; i < 16; ++i) {
        const int qb = i * 256 + wid * 64;       // wave-uniform chunk base
        const int q  = qb + lane;
        const int r  = q >> 5;                   // col row 0..127
        const int kc = (q & 31) ^ (r & 7);       // inverse-swizzled source chunk
        gload_lds16(e + (size_t)(colBase + r) * D_EMB + kc * 8, &bufB[qb * 8]);
    }

    // ---- hoist ALL A fragments into registers (one burst, 32 loads) ----
    const bf16* aB = e + (size_t)(rowBase + wm * 64 + rr) * D_EMB + kh * 8;
    bf16x8 af[8][4];
    #pragma unroll
    for (int t = 0; t < 8; ++t)
        #pragma unroll
        for (int mi = 0; mi < 4; ++mi)
            af[t][mi] = *(const bf16x8*)(aB + (size_t)mi * 16 * D_EMB + t * 32);

    // keep-alive: force all 32 fragments to materialize in VGPRs NOW, so the
    // compiler cannot sink the loads into the K-loop (round-4 failure mode).
    #pragma unroll
    for (int t = 0; t < 8; ++t)
        #pragma unroll
        for (int mi = 0; mi < 4; ++mi) {
            f32x4& kv = *reinterpret_cast<f32x4*>(&af[t][mi]);
            asm volatile("" : "+v"(kv));
        }

    f32x4 acc[4][4];
    #pragma unroll
    for (int i = 0; i < 4; ++i)
        #pragma unroll
        for (int j = 0; j < 4; ++j) acc[i][j] = (f32x4){0.f, 0.f, 0.f, 0.f};

    __syncthreads();   // drains B staging (vmcnt) + labels

    // ---- barrier-free K loop: LDS B frags + register A frags ----
    #pragma unroll
    for (int t = 0; t < 8; ++t) {
        bf16x8 bg[4];
        #pragma unroll
        for (int ni = 0; ni < 4; ++ni) {
            const int colL = wn * 64 + ni * 16 + rr;
            const int kc = t * 4 + kh;
            bg[ni] = *(const bf16x8*)&bufB[(colL * 32 + (kc ^ (colL & 7))) * 8];
        }
        __builtin_amdgcn_s_setprio(1);
        #pragma unroll
        for (int mi = 0; mi < 4; ++mi)
            #pragma unroll
            for (int ni = 0; ni < 4; ++ni)
                acc[mi][ni] = __builtin_amdgcn_mfma_f32_16x16x32_bf16(af[t][mi], bg[ni],
                                                                      acc[mi][ni], 0, 0, 0);
        __builtin_amdgcn_s_setprio(0);
    }

    // ------------- fused epilogue: one exp per element, row + col partials
    const float s = *scale;
    int lc[4];
    #pragma unroll
    for (int ni = 0; ni < 4; ++ni) lc[ni] = labC[wn * 64 + ni * 16 + rr];
    float colA[4] = {0.f, 0.f, 0.f, 0.f}, colB[4] = {0.f, 0.f, 0.f, 0.f};

    #pragma unroll
    for (int mi = 0; mi < 4; ++mi) {
        #pragma unroll
        for (int r = 0; r < 4; ++r) {
            const int rowL = wm * 64 + mi * 16 + kh * 4 + r;
            const int lr = labR[rowL];
            float asum = 0.f, bsum = 0.f;
            #pragma unroll
            for (int ni = 0; ni < 4; ++ni) {
                const int colL = wn * 64 + ni * 16 + rr;
                const float val = acc[mi][ni][r] * s;
                const bool pos = (lr == lc[ni]);
                float ex = __expf(pos ? -val : val);
                if (diag && rowL == colL) ex = 0.f;   // exclude self-pairs
                if (pos) { asum += ex; colA[ni] += ex; }
                else     { bsum += ex; colB[ni] += ex; }
            }
            asum = red16(asum);
            bsum = red16(bsum);
            if (rr == 0) { rowsc[wn][rowL][0] = asum; rowsc[wn][rowL][1] = bsum; }
        }
    }

    if (!diag) {   // col-side (transposed contribution via symmetry)
        #pragma unroll
        for (int ni = 0; ni < 4; ++ni) {
            float a = colA[ni], b = colB[ni];
            a += __shfl_xor(a, 16); a += __shfl_xor(a, 32);
            b += __shfl_xor(b, 16); b += __shfl_xor(b, 32);
            if (lane < 16) {
                colsc[wm][wn * 64 + ni * 16 + lane][0] = a;
                colsc[wm][wn * 64 + ni * 16 + lane][1] = b;
            }
        }
    }
    __syncthreads();

    if (tid < PAN) {
        const float ra = rowsc[0][tid][0] + rowsc[1][tid][0];
        const float rb = rowsc[0][tid][1] + rowsc[1][tid][1];
        wsAB[(size_t)bx * N_EMB + rowBase + tid] = packbf(ra, rb);
        if (!diag) {
            const float ca = colsc[0][tid][0] + colsc[1][tid][0];
            const float cb = colsc[0][tid][1] + colsc[1][tid][1];
            wsAB[(size_t)by * N_EMB + colBase + tid] = packbf(ca, cb);
        }
    }
}

// --------------------------------------------------- per-row + segment reduce
__global__ __launch_bounds__(256) void reduce_rows(const unsigned* __restrict__ wsAB,
                                                   const int* __restrict__ labels,
                                                   float* __restrict__ part) {
    __shared__ float A[NUM_LABELS], B[NUM_LABELS];
    __shared__ int C[NUM_LABELS];
    const int tid = threadIdx.x;
    if (tid < NUM_LABELS) { A[tid] = 0.f; B[tid] = 0.f; C[tid] = 0; }
    __syncthreads();
    const int row = blockIdx.x * 256 + tid;
    float a = 0.f, b = 0.f;
    #pragma unroll
    for (int p = 0; p < NPAN; ++p) {
        const unsigned u = wsAB[(size_t)p * N_EMB + row];
        a += __builtin_bit_cast(float, u << 16);
        b += __builtin_bit_cast(float, u & 0xFFFF0000u);
    }
    const int l = labels[row];
    atomicAdd(&A[l], a);
    atomicAdd(&B[l], b);
    atomicAdd(&C[l], 1);
    __syncthreads();
    if (tid < NUM_LABELS) {
        float* p = part + ((size_t)blockIdx.x * NUM_LABELS + tid) * 3;
        p[0] = A[tid]; p[1] = B[tid]; p[2] = (float)C[tid];
    }
}

// ----------------------------------------------------------------- finalize
__global__ __launch_bounds__(128) void finalize_kernel(const float* __restrict__ part,
                                                       float* __restrict__ out) {
    const int tid = threadIdx.x;   // label id
    float A = 0.f, B = 0.f, c = 0.f;
    #pragma unroll
    for (int blk = 0; blk < 32; ++blk) {
        const float* p = part + ((size_t)blk * NUM_LABELS + tid) * 3;
        A += p[0]; B += p[1]; c += p[2];
    }
    float v = (c >= 2.f) ? A * B : 0.f;
    #pragma unroll
    for (int off = 32; off >= 1; off >>= 1) v += __shfl_xor(v, off);
    __shared__ float w2[2];
    if ((tid & 63) == 0) w2[tid >> 6] = v;
    __syncthreads();
    if (tid == 0) out[0] = logf(1.0f + w2[0] + w2[1]);
}

// ------------------------------------------------------------------ launcher
extern "C" void kernel_launch(void* const* d_in, const int* in_sizes, int n_in,
                              void* d_out, int out_size, void* d_ws, size_t ws_size,
                              hipStream_t stream) {
    const float* emb    = (const float*)d_in[0];
    const int*   labels = (const int*)d_in[1];
    const float* scale  = (const float*)d_in[2];
    float* out = (float*)d_out;

    bf16*     e16  = (bf16*)d_ws;                                     // 4 MB
    unsigned* wsAB = (unsigned*)((char*)d_ws + (size_t)N_EMB * D_EMB * sizeof(bf16)); // 2 MB
    float*    part = (float*)((char*)wsAB + (size_t)NPAN * N_EMB * sizeof(unsigned)); // 48 KB

    normalize_kernel<<<N_EMB / 4, 256, 0, stream>>>(emb, e16);
    cosent_main<<<NTRI, 256, 0, stream>>>(e16, labels, scale, wsAB);
    reduce_rows<<<N_EMB / 256, 256, 0, stream>>>(wsAB, labels, part);
    finalize_kernel<<<1, 128, 0, stream>>>(part, out);
}